// Round 9
// baseline (437.939 us; speedup 1.0000x reference)
//
#include <hip/hip_runtime.h>
#include <hip/hip_fp16.h>
#include <hip/hip_cooperative_groups.h>

namespace cg = cooperative_groups;

#define N_NODES_C 100000
#define N_EDGES_C 1600000
#define IN_F 128
#define OUT_F 64

#define BIN_SHIFT 9
#define BIN_SZ    512                                  // nodes per bin
#define NBIN      ((N_NODES_C + BIN_SZ - 1) / BIN_SZ)  // 196
#define NCHUNK    256
#define CH        (N_EDGES_C / NCHUNK)                 // 6250 exactly

typedef __attribute__((ext_vector_type(8))) _Float16 half8;
typedef __attribute__((ext_vector_type(4))) float    f32x4;

// ---------------- GEMM via MFMA (exact R4/R8 body — proven) ----------------
__global__ __launch_bounds__(256) void gemm_mfma_kernel(
    const float* __restrict__ x, const float* __restrict__ W,
    const float* __restrict__ bias, _Float16* __restrict__ h, int n) {
  const int wid  = threadIdx.x >> 6;
  const int lane = threadIdx.x & 63;
  const int lr   = lane & 15;   // A-row / B-col / D-col
  const int lg   = lane >> 4;   // k-group (and D row-group)

  const int tile = blockIdx.x * 4 + wid;
  if (tile * 16 >= n) return;
  const int node0 = tile * 16;

  half8 bfrag[4][4];
#pragma unroll
  for (int nc = 0; nc < 4; ++nc) {
    const float* wrow = W + (size_t)(nc * 16 + lr) * IN_F + lg * 8;
#pragma unroll
    for (int kc = 0; kc < 4; ++kc) {
      float4 a = ((const float4*)(wrow + kc * 32))[0];
      float4 b = ((const float4*)(wrow + kc * 32))[1];
      half8 f;
      f[0] = (_Float16)a.x; f[1] = (_Float16)a.y;
      f[2] = (_Float16)a.z; f[3] = (_Float16)a.w;
      f[4] = (_Float16)b.x; f[5] = (_Float16)b.y;
      f[6] = (_Float16)b.z; f[7] = (_Float16)b.w;
      bfrag[nc][kc] = f;
    }
  }

  float bv[4];
#pragma unroll
  for (int nc = 0; nc < 4; ++nc) bv[nc] = bias[nc * 16 + lr];

  const float* xp = x + (size_t)(node0 + lr) * IN_F + lg * 8;
  f32x4 acc[4] = {{0.f, 0.f, 0.f, 0.f}, {0.f, 0.f, 0.f, 0.f},
                  {0.f, 0.f, 0.f, 0.f}, {0.f, 0.f, 0.f, 0.f}};
#pragma unroll
  for (int kc = 0; kc < 4; ++kc) {
    float4 a = ((const float4*)(xp + kc * 32))[0];
    float4 b = ((const float4*)(xp + kc * 32))[1];
    half8 af;
    af[0] = (_Float16)a.x; af[1] = (_Float16)a.y;
    af[2] = (_Float16)a.z; af[3] = (_Float16)a.w;
    af[4] = (_Float16)b.x; af[5] = (_Float16)b.y;
    af[6] = (_Float16)b.z; af[7] = (_Float16)b.w;
#pragma unroll
    for (int nc = 0; nc < 4; ++nc)
      acc[nc] = __builtin_amdgcn_mfma_f32_16x16x32_f16(af, bfrag[nc][kc], acc[nc], 0, 0, 0);
  }

#pragma unroll
  for (int nc = 0; nc < 4; ++nc) {
#pragma unroll
    for (int r = 0; r < 4; ++r) {
      int node = node0 + lg * 4 + r;
      h[(size_t)node * OUT_F + nc * 16 + lr] = (_Float16)(acc[nc][r] + bv[nc]);
    }
  }
}

// ---------------- Cooperative CSR build: 6 dispatches -> 1 ----------------
// Phase bodies are the R4-proven kernels verbatim; 5 grid.sync()s replace 5
// kernel boundaries. Grid = 256 blocks x 1024 thr = 1 block/CU (co-resident).
__global__ __launch_bounds__(1024) void mega_csr_kernel(
    const int* __restrict__ src, const int* __restrict__ dst,
    const float* __restrict__ ew, int* __restrict__ hist,
    int* __restrict__ rowTot, int* __restrict__ binStart,
    int* __restrict__ soff, int* __restrict__ stage_d,
    int2* __restrict__ stage_sw, int* __restrict__ row_ptr,
    int2* __restrict__ edges, int n) {
  cg::grid_group grid = cg::this_grid();
  const int t   = threadIdx.x;
  const int bid = blockIdx.x;

  __shared__ int hh[NBIN];
  __shared__ int red[16];
  __shared__ int s3[256];
  __shared__ int wsum[16];
  __shared__ int lcur[NBIN];
  __shared__ int lcount[BIN_SZ];
  __shared__ int s6[BIN_SZ];
  __shared__ int lcur6[BIN_SZ];

  // ---- P1: per-chunk LDS histogram (== hist_kernel) ----
  if (bid < NCHUNK) {
    for (int i = t; i < NBIN; i += 1024) hh[i] = 0;
    __syncthreads();
    const int e0 = bid * CH;
    for (int i = t; i < CH; i += 1024)
      atomicAdd(&hh[dst[e0 + i] >> BIN_SHIFT], 1);
    __syncthreads();
    for (int i = t; i < NBIN; i += 1024)
      hist[i * NCHUNK + bid] = hh[i];          // bin-major layout
  }
  grid.sync();

  // ---- P2: bin-row totals ----
  if (bid < NBIN) {
    int v = (t < NCHUNK) ? hist[bid * NCHUNK + t] : 0;
#pragma unroll
    for (int off = 1; off < 64; off <<= 1) v += __shfl_xor(v, off);
    if ((t & 63) == 0) red[t >> 6] = v;
    __syncthreads();
    if (t == 0) rowTot[bid] = red[0] + red[1] + red[2] + red[3];
  }
  grid.sync();

  // ---- P3: scan 196 totals -> binStart (block 0) ----
  if (bid == 0) {
    int v = (t < NBIN) ? rowTot[t] : 0;
    if (t < 256) s3[t] = v;
    __syncthreads();
    for (int off = 1; off < 256; off <<= 1) {
      int u = 0;
      if (t < 256 && t >= off) u = s3[t - off];
      __syncthreads();
      if (t < 256) s3[t] += u;
      __syncthreads();
    }
    if (t < NBIN) binStart[t] = s3[t] - v;     // exclusive over bins
  }
  grid.sync();

  // ---- P4: per-row exclusive scan + base -> soff ----
  if (bid < NBIN) {
    int base = binStart[bid];
    int v = (t < NCHUNK) ? hist[bid * NCHUNK + t] : 0;
    int ls = v;
#pragma unroll
    for (int off = 1; off < 64; off <<= 1) {
      int u = __shfl_up(ls, off);
      if ((t & 63) >= off) ls += u;
    }
    if ((t & 63) == 63) wsum[t >> 6] = ls;
    __syncthreads();
    int wv = t >> 6;
    int woff = 0;
    if (wv >= 1) woff = wsum[0];
    if (wv >= 2) woff += wsum[1];
    if (wv >= 3) woff += wsum[2];
    if (t < NCHUNK) soff[bid * NCHUNK + t] = base + woff + ls - v;
  }
  grid.sync();

  // ---- P5: binscatter (== binscatter_kernel) ----
  if (bid < NCHUNK) {
    for (int i = t; i < NBIN; i += 1024) lcur[i] = soff[i * NCHUNK + bid];
    __syncthreads();
    const int e0 = bid * CH;
    for (int i = t; i < CH; i += 1024) {
      int e = e0 + i;
      int d = dst[e];
      int p = atomicAdd(&lcur[d >> BIN_SHIFT], 1);
      stage_d[p]  = d;
      stage_sw[p] = make_int2(src[e] * OUT_F, __float_as_int(ew[e]));
    }
  }
  grid.sync();

  // ---- P6: place (== place_kernel) ----
  if (bid < NBIN) {
    const int base = binStart[bid];
    const int end  = (bid == NBIN - 1) ? N_EDGES_C : binStart[bid + 1];
    const int node0 = bid << BIN_SHIFT;

    if (t < BIN_SZ) lcount[t] = 0;
    __syncthreads();
    for (int i = base + t; i < end; i += 1024)
      atomicAdd(&lcount[stage_d[i] - node0], 1);
    __syncthreads();

    int v = 0;
    if (t < BIN_SZ) { v = lcount[t]; s6[t] = v; }
    __syncthreads();
    for (int off = 1; off < BIN_SZ; off <<= 1) {
      int u = (t < BIN_SZ && t >= off) ? s6[t - off] : 0;
      __syncthreads();
      if (t < BIN_SZ) s6[t] += u;
      __syncthreads();
    }
    if (t < BIN_SZ) {
      int ex = base + s6[t] - v;
      int node = node0 + t;
      if (node < n) row_ptr[node] = ex;
      lcur6[t] = ex;
    }
    __syncthreads();

    for (int i = base + t; i < end; i += 1024) {
      int d = stage_d[i];
      int p = atomicAdd(&lcur6[d - node0], 1);
      edges[p] = stage_sw[i];
    }
    if (bid == NBIN - 1 && t == 0) row_ptr[n] = N_EDGES_C;
  }
}

// ---------------- SpMM hop (fp16 rows, exact R4/R8 body) ----------------
__device__ inline void fma8_h(float* acc, uint4 r, float w) {
  unsigned u[4] = {r.x, r.y, r.z, r.w};
#pragma unroll
  for (int q = 0; q < 4; ++q) {
    __half2 h2 = *reinterpret_cast<__half2*>(&u[q]);
    float2 f = __half22float2(h2);
    acc[2 * q + 0] += w * f.x;
    acc[2 * q + 1] += w * f.y;
  }
}

template <int OUT32>
__global__ __launch_bounds__(256) void spmm16_kernel(
    const int* __restrict__ row_ptr, const int2* __restrict__ edges,
    const __half* __restrict__ hin, void* __restrict__ hout, int n) {
  const int node = blockIdx.x * 32 + (threadIdx.x >> 3);
  const int fl   = threadIdx.x & 7;     // feature octet
  if (node >= n) return;
  const int beg = row_ptr[node];
  const int end = row_ptr[node + 1];

  float acc[8] = {0.f, 0.f, 0.f, 0.f, 0.f, 0.f, 0.f, 0.f};
  int j = beg;
  for (; j + 3 < end; j += 4) {
    int2 e0 = edges[j + 0];
    int2 e1 = edges[j + 1];
    int2 e2 = edges[j + 2];
    int2 e3 = edges[j + 3];
    uint4 r0 = ((const uint4*)(hin + e0.x))[fl];
    uint4 r1 = ((const uint4*)(hin + e1.x))[fl];
    uint4 r2 = ((const uint4*)(hin + e2.x))[fl];
    uint4 r3 = ((const uint4*)(hin + e3.x))[fl];
    fma8_h(acc, r0, __int_as_float(e0.y));
    fma8_h(acc, r1, __int_as_float(e1.y));
    fma8_h(acc, r2, __int_as_float(e2.y));
    fma8_h(acc, r3, __int_as_float(e3.y));
  }
  for (; j < end; ++j) {
    int2 e = edges[j];
    uint4 r = ((const uint4*)(hin + e.x))[fl];
    fma8_h(acc, r, __int_as_float(e.y));
  }

  if (OUT32) {
    float* op = (float*)hout + (size_t)node * OUT_F + 8 * fl;
    ((float4*)op)[0] = make_float4(acc[0], acc[1], acc[2], acc[3]);
    ((float4*)op)[1] = make_float4(acc[4], acc[5], acc[6], acc[7]);
  } else {
    union { __half2 h2[4]; uint4 u; } pk;
#pragma unroll
    for (int q = 0; q < 4; ++q)
      pk.h2[q] = __floats2half2_rn(acc[2 * q], acc[2 * q + 1]);
    ((uint4*)((char*)hout + (size_t)node * 128))[fl] = pk.u;
  }
}

extern "C" void kernel_launch(void* const* d_in, const int* in_sizes, int n_in,
                              void* d_out, int out_size, void* d_ws, size_t ws_size,
                              hipStream_t stream) {
  const float* x    = (const float*)d_in[0];
  const int*   ei   = (const int*)d_in[1];   // int32 (harness materializes ints as int32)
  const float* ew   = (const float*)d_in[2];
  const float* W    = (const float*)d_in[3];
  const float* bias = (const float*)d_in[4];
  float* out = (float*)d_out;

  const int N = N_NODES_C;
  const int E = N_EDGES_C;
  const int* src = ei;
  const int* dst = ei + E;
  const int NH = NBIN * NCHUNK;        // 50176 hist entries

  char* p = (char*)d_ws;
  auto carve = [&](size_t bytes) {
    void* r = (void*)p;
    p += (bytes + 255) & ~(size_t)255;
    return r;
  };
  __half* h16A     = (__half*)carve((size_t)N * OUT_F * 2);
  __half* h16B     = (__half*)carve((size_t)N * OUT_F * 2);
  int*   row_ptr   = (int*)  carve((size_t)(N + 1) * 4);
  int2*  edges     = (int2*) carve((size_t)E * 8);
  int*   hist      = (int*)  carve((size_t)NH * 4);
  int*   soff      = (int*)  carve((size_t)NH * 4);
  int*   rowTot    = (int*)  carve((size_t)NBIN * 4);
  int*   binStart  = (int*)  carve((size_t)(NBIN + 1) * 4);

  // staging in d_out (free scratch until the final hop): sw 12.8MB + d 6.4MB
  int2* stage_sw = (int2*)d_out;
  int*  stage_d  = (int*)((char*)d_out + (size_t)E * 8);

  // 1. CSR build: one cooperative launch, 5 grid.syncs (was 6 dispatches)
  {
    int Nv = N;
    void* margs[] = {(void*)&src, (void*)&dst, (void*)&ew, (void*)&hist,
                     (void*)&rowTot, (void*)&binStart, (void*)&soff,
                     (void*)&stage_d, (void*)&stage_sw, (void*)&row_ptr,
                     (void*)&edges, (void*)&Nv};
    hipLaunchCooperativeKernel((void*)mega_csr_kernel, dim3(NCHUNK), dim3(1024),
                               margs, 0, stream);
  }

  // 2. h0 = fp16(x @ W^T + b) via MFMA (proven shape)
  gemm_mfma_kernel<<<(N / 16 + 3) / 4, 256, 0, stream>>>(x, W, bias, (_Float16*)h16A, N);

  // 3-5. three hops: fp16 -> fp16 -> fp16 -> fp32(out)
  spmm16_kernel<0><<<(N + 31) / 32, 256, 0, stream>>>(row_ptr, edges, h16A, h16B, N);
  spmm16_kernel<0><<<(N + 31) / 32, 256, 0, stream>>>(row_ptr, edges, h16B, h16A, N);
  spmm16_kernel<1><<<(N + 31) / 32, 256, 0, stream>>>(row_ptr, edges, h16A, out, N);
}